// Round 1
// baseline (672.990 us; speedup 1.0000x reference)
//
#include <hip/hip_runtime.h>
#include <hip/hip_bf16.h>
#include <stdint.h>

#define NN 100000
#define NE 1600000
#define CH 128
#define OC 64
#define NG 512

// ---------------- degree ----------------
__global__ __launch_bounds__(256) void k_deg(const int* __restrict__ dst,
                                             int* __restrict__ deg, int E) {
    int i = blockIdx.x * 256 + threadIdx.x;
    if (i < E) atomicAdd(&deg[dst[i]], 1);
}

__global__ __launch_bounds__(256) void k_dinv(const int* __restrict__ deg,
                                              float* __restrict__ dinv, int n) {
    int i = blockIdx.x * 256 + threadIdx.x;
    if (i < n) dinv[i] = rsqrtf((float)deg[i] + 1.0f);
}

// ---------------- prefix scan (3-phase, 1024 elems/block) ----------------
__global__ __launch_bounds__(256) void k_scan1(const int* __restrict__ deg,
                                               int* __restrict__ excl,
                                               int* __restrict__ bsums, int n) {
    __shared__ int sd[256];
    int tid = threadIdx.x;
    int base = blockIdx.x * 1024 + tid * 4;
    int v[4];
#pragma unroll
    for (int i = 0; i < 4; i++) v[i] = (base + i < n) ? deg[base + i] : 0;
    int tsum = v[0] + v[1] + v[2] + v[3];
    int val = tsum;
    sd[tid] = val; __syncthreads();
    for (int off = 1; off < 256; off <<= 1) {
        int t = (tid >= off) ? sd[tid - off] : 0;
        __syncthreads();
        val += t; sd[tid] = val;
        __syncthreads();
    }
    int run = val - tsum;  // exclusive prefix for this thread's first elem
#pragma unroll
    for (int i = 0; i < 4; i++) {
        if (base + i < n) excl[base + i] = run;
        run += v[i];
    }
    if (tid == 255) bsums[blockIdx.x] = val;
}

__global__ __launch_bounds__(128) void k_scan2(int* __restrict__ bs, int nb) {
    __shared__ int sd[128];
    int tid = threadIdx.x;
    int v = (tid < nb) ? bs[tid] : 0;
    int val = v;
    sd[tid] = val; __syncthreads();
    for (int off = 1; off < 128; off <<= 1) {
        int t = (tid >= off) ? sd[tid - off] : 0;
        __syncthreads();
        val += t; sd[tid] = val;
        __syncthreads();
    }
    if (tid < nb) bs[tid] = val - v;  // exclusive block offsets, in place
}

__global__ __launch_bounds__(256) void k_scan3(const int* __restrict__ excl,
                                               const int* __restrict__ boff,
                                               int* __restrict__ row_start,
                                               int* __restrict__ cursor,
                                               int n, int E) {
    int i = blockIdx.x * 256 + threadIdx.x;
    if (i < n) {
        int rs = excl[i] + boff[i >> 10];
        row_start[i] = rs;
        cursor[i] = rs;
    }
    if (i == 0) row_start[n] = E;
}

// ---------------- bucket edges by dst ----------------
__global__ __launch_bounds__(256) void k_scatter(const int* __restrict__ src,
                                                 const int* __restrict__ dst,
                                                 const float* __restrict__ dinv,
                                                 int* __restrict__ cursor,
                                                 int* __restrict__ ssrc,
                                                 float* __restrict__ sw, int E) {
    int i = blockIdx.x * 256 + threadIdx.x;
    if (i >= E) return;
    int s = src[i], d = dst[i];
    int pos = atomicAdd(&cursor[d], 1);
    ssrc[pos] = s;
    sw[pos] = dinv[s] * dinv[d];
}

// ---------------- aggregation: out = A_hat * H (one wave per node) ----------
__global__ __launch_bounds__(256) void k_agg(const float* __restrict__ H,
                                             const int* __restrict__ rs,
                                             const int* __restrict__ ssrc,
                                             const float* __restrict__ sw,
                                             const float* __restrict__ dinv,
                                             float* __restrict__ out, int n) {
    int wid = (blockIdx.x << 2) | (threadIdx.x >> 6);
    int lane = threadIdx.x & 63;
    if (wid >= n) return;
    int c = lane * 2;
    float d = dinv[wid];
    float2 hv = *(const float2*)(H + (size_t)wid * CH + c);
    float a0 = hv.x * d * d;
    float a1 = hv.y * d * d;
    int e0 = rs[wid], e1 = rs[wid + 1];
    int e = e0;
    if (e < e1) {
        int s = ssrc[e];
        float w = sw[e];
        for (; e + 1 < e1; ++e) {
            int s2 = ssrc[e + 1];
            float w2 = sw[e + 1];
            float2 g = *(const float2*)(H + (size_t)s * CH + c);
            a0 += g.x * w; a1 += g.y * w;
            s = s2; w = w2;
        }
        float2 g = *(const float2*)(H + (size_t)s * CH + c);
        a0 += g.x * w; a1 += g.y * w;
    }
    float2 o; o.x = a0; o.y = a1;
    *(float2*)(out + (size_t)wid * CH + c) = o;
}

// ---------------- H = relu(Y*W + b), Y:[n,128] W:[128,128] ----------------
__global__ __launch_bounds__(256) void k_gemm_relu(const float* __restrict__ Y,
                                                   const float* __restrict__ W,
                                                   const float* __restrict__ bias,
                                                   float* __restrict__ H, int n) {
    __shared__ __align__(16) float As[64][68];  // [k][row] (Y tile transposed)
    __shared__ __align__(16) float Bs[64][68];  // [k][col]
    int tid = threadIdx.x;
    int tx = tid & 15, ty = tid >> 4;
    int r0 = blockIdx.y * 64, c0 = blockIdx.x * 64;
    float acc[4][4] = {};
    for (int kt = 0; kt < 2; ++kt) {
        {
            int row = tid >> 4;        // 0..15 (+16*i)
            int kk = (tid & 15) * 4;   // 0,4,...,60
#pragma unroll
            for (int i = 0; i < 4; i++) {
                int r = r0 + row + i * 16;
                float4 v = make_float4(0.f, 0.f, 0.f, 0.f);
                if (r < n) v = *(const float4*)(Y + (size_t)r * CH + kt * 64 + kk);
                As[kk + 0][row + i * 16] = v.x;
                As[kk + 1][row + i * 16] = v.y;
                As[kk + 2][row + i * 16] = v.z;
                As[kk + 3][row + i * 16] = v.w;
            }
        }
        {
#pragma unroll
            for (int i = 0; i < 4; i++) {
                int f = tid + i * 256;       // 0..1023
                int kk = f >> 4;             // 0..63
                int c4 = (f & 15) * 4;
                float4 v = *(const float4*)(W + (size_t)(kt * 64 + kk) * CH + c0 + c4);
                *(float4*)&Bs[kk][c4] = v;
            }
        }
        __syncthreads();
#pragma unroll 8
        for (int k = 0; k < 64; ++k) {
            float4 a = *(float4*)&As[k][ty * 4];
            float4 b = *(float4*)&Bs[k][tx * 4];
            acc[0][0] += a.x * b.x; acc[0][1] += a.x * b.y; acc[0][2] += a.x * b.z; acc[0][3] += a.x * b.w;
            acc[1][0] += a.y * b.x; acc[1][1] += a.y * b.y; acc[1][2] += a.y * b.z; acc[1][3] += a.y * b.w;
            acc[2][0] += a.z * b.x; acc[2][1] += a.z * b.y; acc[2][2] += a.z * b.z; acc[2][3] += a.z * b.w;
            acc[3][0] += a.w * b.x; acc[3][1] += a.w * b.y; acc[3][2] += a.w * b.z; acc[3][3] += a.w * b.w;
        }
        __syncthreads();
    }
    float4 bv = *(const float4*)(bias + c0 + tx * 4);
#pragma unroll
    for (int i = 0; i < 4; i++) {
        int r = r0 + ty * 4 + i;
        if (r >= n) continue;
        float4 o;
        o.x = fmaxf(acc[i][0] + bv.x, 0.f);
        o.y = fmaxf(acc[i][1] + bv.y, 0.f);
        o.z = fmaxf(acc[i][2] + bv.z, 0.f);
        o.w = fmaxf(acc[i][3] + bv.w, 0.f);
        *(float4*)(H + (size_t)r * CH + c0 + tx * 4) = o;
    }
}

// ---------------- mean pool over sorted batch ids ----------------
__global__ __launch_bounds__(128) void k_pool(const float* __restrict__ Z,
                                              const int* __restrict__ batch,
                                              float* __restrict__ Q, int n) {
    int g = blockIdx.x;
    int c = threadIdx.x;
    int lo = 0, hi = n;
    while (lo < hi) { int m = (lo + hi) >> 1; if (batch[m] < g) lo = m + 1; else hi = m; }
    int start = lo;
    lo = start; hi = n;
    while (lo < hi) { int m = (lo + hi) >> 1; if (batch[m] < g + 1) lo = m + 1; else hi = m; }
    int end = lo;
    float acc = 0.f;
    for (int i = start; i < end; ++i) acc += Z[(size_t)i * CH + c];
    int cnt = end - start;
    Q[g * CH + c] = acc / (float)(cnt > 0 ? cnt : 1);
}

// ---------------- fold W2*Wfc, b2*Wfc+bfc ----------------
__global__ __launch_bounds__(256) void k_foldw(const float* __restrict__ W2,
                                               const float* __restrict__ b2,
                                               const float* __restrict__ Wfc,
                                               const float* __restrict__ bfc,
                                               float* __restrict__ Wc,
                                               float* __restrict__ bc) {
    int t = blockIdx.x * 256 + threadIdx.x;
    if (t < CH * OC) {
        int k = t >> 6, o = t & 63;
        float acc = 0.f;
        for (int j = 0; j < CH; j++) acc += W2[k * CH + j] * Wfc[j * OC + o];
        Wc[t] = acc;
    } else if (t < CH * OC + OC) {
        int o = t - CH * OC;
        float acc = bfc[o];
        for (int j = 0; j < CH; j++) acc += b2[j] * Wfc[j * OC + o];
        bc[o] = acc;
    }
}

// ---------------- out = Q*Wc + bc ----------------
__global__ __launch_bounds__(256) void k_out(const float* __restrict__ Q,
                                             const float* __restrict__ Wc,
                                             const float* __restrict__ bc,
                                             float* __restrict__ out) {
    int t = blockIdx.x * 256 + threadIdx.x;  // 512*64
    int g = t >> 6, o = t & 63;
    float acc = bc[o];
    for (int k = 0; k < CH; k++) acc += Q[g * CH + k] * Wc[k * OC + o];
    out[t] = acc;
}

extern "C" void kernel_launch(void* const* d_in, const int* in_sizes, int n_in,
                              void* d_out, int out_size, void* d_ws, size_t ws_size,
                              hipStream_t stream) {
    const float* x   = (const float*)d_in[0];
    const float* W1  = (const float*)d_in[1];
    const float* b1  = (const float*)d_in[2];
    const float* W2  = (const float*)d_in[3];
    const float* b2  = (const float*)d_in[4];
    const float* Wfc = (const float*)d_in[5];
    const float* bfc = (const float*)d_in[6];
    const int* edges = (const int*)d_in[7];
    const int* batch = (const int*)d_in[8];

    const int n = in_sizes[8];        // 100000
    const int E = in_sizes[7] / 2;    // 1600000
    const int* esrc = edges;
    const int* edst = edges + E;

    // workspace carve-up (all 256B aligned)
    char* p = (char*)d_ws;
    auto carve = [&](size_t bytes) {
        void* r = (void*)p;
        p += (bytes + 255) & ~(size_t)255;
        return r;
    };
    int*   deg       = (int*)carve((size_t)n * 4);
    float* dinv      = (float*)carve((size_t)n * 4);
    int*   excl      = (int*)carve((size_t)n * 4);
    int*   bsums     = (int*)carve(512);
    int*   row_start = (int*)carve((size_t)(n + 1) * 4);
    int*   cursor    = (int*)carve((size_t)n * 4);
    int*   ssrc      = (int*)carve((size_t)E * 4);
    float* sw        = (float*)carve((size_t)E * 4);
    float* y         = (float*)carve((size_t)n * CH * 4);  // also reused as z
    float* h1        = (float*)carve((size_t)n * CH * 4);
    float* q         = (float*)carve((size_t)NG * CH * 4);
    float* Wc        = (float*)carve((size_t)CH * OC * 4);
    float* bc        = (float*)carve((size_t)OC * 4);

    hipMemsetAsync(deg, 0, (size_t)n * 4, stream);

    int gE = (E + 255) / 256;
    int gN = (n + 255) / 256;
    int nScanBlocks = (n + 1023) / 1024;

    k_deg<<<gE, 256, 0, stream>>>(edst, deg, E);
    k_dinv<<<gN, 256, 0, stream>>>(deg, dinv, n);
    k_scan1<<<nScanBlocks, 256, 0, stream>>>(deg, excl, bsums, n);
    k_scan2<<<1, 128, 0, stream>>>(bsums, nScanBlocks);
    k_scan3<<<gN, 256, 0, stream>>>(excl, bsums, row_start, cursor, n, E);
    k_scatter<<<gE, 256, 0, stream>>>(esrc, edst, dinv, cursor, ssrc, sw, E);

    // y = A_hat * x
    k_agg<<<(n + 3) / 4, 256, 0, stream>>>(x, row_start, ssrc, sw, dinv, y, n);
    // h1 = relu(y*W1 + b1)
    dim3 gg(CH / 64, (n + 63) / 64);
    k_gemm_relu<<<gg, 256, 0, stream>>>(y, W1, b1, h1, n);
    // z = A_hat * h1   (z reuses y)
    k_agg<<<(n + 3) / 4, 256, 0, stream>>>(h1, row_start, ssrc, sw, dinv, y, n);
    // q = pool(z)
    k_pool<<<NG, 128, 0, stream>>>(y, batch, q, n);
    // folded tail
    k_foldw<<<(CH * OC + OC + 255) / 256, 256, 0, stream>>>(W2, b2, Wfc, bfc, Wc, bc);
    k_out<<<(NG * OC + 255) / 256, 256, 0, stream>>>(q, Wc, bc, (float*)d_out);
}

// Round 2
// 644.987 us; speedup vs baseline: 1.0434x; 1.0434x over previous
//
#include <hip/hip_runtime.h>
#include <stdint.h>

#define NN 100000
#define NE 1600000
#define CH 128
#define OC 64
#define NG 512

typedef unsigned int uint;
typedef unsigned short ushort;

__device__ __forceinline__ ushort f2bf(float f) {
    uint u = __float_as_uint(f);
    uint r = u + 0x7fffu + ((u >> 16) & 1u);  // round-to-nearest-even
    return (ushort)(r >> 16);
}
__device__ __forceinline__ float bf_lo(uint g) { return __uint_as_float(g << 16); }
__device__ __forceinline__ float bf_hi(uint g) { return __uint_as_float(g & 0xffff0000u); }

// ---------------- fp32 -> bf16 bulk convert ----------------
__global__ __launch_bounds__(256) void k_cvt(const float* __restrict__ x,
                                             ushort* __restrict__ xb, int total) {
    int i = (blockIdx.x * 256 + threadIdx.x) * 4;
    if (i >= total) return;
    float4 v = *(const float4*)(x + i);
    uint2 o;
    o.x = (uint)f2bf(v.x) | ((uint)f2bf(v.y) << 16);
    o.y = (uint)f2bf(v.z) | ((uint)f2bf(v.w) << 16);
    *(uint2*)(xb + i) = o;
}

// ---------------- degree ----------------
__global__ __launch_bounds__(256) void k_deg(const int* __restrict__ dst,
                                             int* __restrict__ deg, int E) {
    int i = blockIdx.x * 256 + threadIdx.x;
    if (i < E) atomicAdd(&deg[dst[i]], 1);
}

// ---------------- prefix scan (3-phase, 1024 elems/block) + dinv ----------------
__global__ __launch_bounds__(256) void k_scan1(const int* __restrict__ deg,
                                               int* __restrict__ excl,
                                               int* __restrict__ bsums,
                                               float* __restrict__ dinv, int n) {
    __shared__ int sd[256];
    int tid = threadIdx.x;
    int base = blockIdx.x * 1024 + tid * 4;
    int v[4];
#pragma unroll
    for (int i = 0; i < 4; i++) v[i] = (base + i < n) ? deg[base + i] : 0;
#pragma unroll
    for (int i = 0; i < 4; i++)
        if (base + i < n) dinv[base + i] = rsqrtf((float)v[i] + 1.0f);
    int tsum = v[0] + v[1] + v[2] + v[3];
    int val = tsum;
    sd[tid] = val; __syncthreads();
    for (int off = 1; off < 256; off <<= 1) {
        int t = (tid >= off) ? sd[tid - off] : 0;
        __syncthreads();
        val += t; sd[tid] = val;
        __syncthreads();
    }
    int run = val - tsum;
#pragma unroll
    for (int i = 0; i < 4; i++) {
        if (base + i < n) excl[base + i] = run;
        run += v[i];
    }
    if (tid == 255) bsums[blockIdx.x] = val;
}

__global__ __launch_bounds__(128) void k_scan2(int* __restrict__ bs, int nb) {
    __shared__ int sd[128];
    int tid = threadIdx.x;
    int v = (tid < nb) ? bs[tid] : 0;
    int val = v;
    sd[tid] = val; __syncthreads();
    for (int off = 1; off < 128; off <<= 1) {
        int t = (tid >= off) ? sd[tid - off] : 0;
        __syncthreads();
        val += t; sd[tid] = val;
        __syncthreads();
    }
    if (tid < nb) bs[tid] = val - v;
}

__global__ __launch_bounds__(256) void k_scan3(const int* __restrict__ excl,
                                               const int* __restrict__ boff,
                                               int* __restrict__ row_start,
                                               int* __restrict__ cursor,
                                               int n, int E) {
    int i = blockIdx.x * 256 + threadIdx.x;
    if (i < n) {
        int rs = excl[i] + boff[i >> 10];
        row_start[i] = rs;
        cursor[i] = rs;
    }
    if (i == 0) row_start[n] = E;
}

// ---------------- bucket edges by dst: single packed 8B store ----------------
__global__ __launch_bounds__(256) void k_scatter(const int* __restrict__ src,
                                                 const int* __restrict__ dst,
                                                 const float* __restrict__ dinv,
                                                 int* __restrict__ cursor,
                                                 int2* __restrict__ ew, int E) {
    int i = blockIdx.x * 256 + threadIdx.x;
    if (i >= E) return;
    int s = src[i], d = dst[i];
    int pos = atomicAdd(&cursor[d], 1);
    int2 pk;
    pk.x = s;
    pk.y = __float_as_int(dinv[s] * dinv[d]);
    ew[pos] = pk;
}

// ---------------- aggregation (bf16 in, bf16 out): out = A_hat * H ----------
__global__ __launch_bounds__(256) void k_agg(const ushort* __restrict__ H,
                                             const int* __restrict__ rs,
                                             const int2* __restrict__ ew,
                                             const float* __restrict__ dinv,
                                             ushort* __restrict__ out, int n) {
    int wid = (blockIdx.x << 2) | (threadIdx.x >> 6);
    int lane = threadIdx.x & 63;
    if (wid >= n) return;
    int c = lane * 2;
    uint selfv = *(const uint*)(H + (size_t)wid * CH + c);
    float d = dinv[wid];
    float dd = d * d;
    float a0 = bf_lo(selfv) * dd;
    float a1 = bf_hi(selfv) * dd;
    int e0 = rs[wid], e1 = rs[wid + 1];
    int e = e0;
    if (e < e1) {
        int2 pk = ew[e];
        for (; e + 1 < e1; ++e) {
            int2 nx = ew[e + 1];
            float w = __int_as_float(pk.y);
            uint g = *(const uint*)(H + (size_t)pk.x * CH + c);
            a0 = fmaf(bf_lo(g), w, a0);
            a1 = fmaf(bf_hi(g), w, a1);
            pk = nx;
        }
        float w = __int_as_float(pk.y);
        uint g = *(const uint*)(H + (size_t)pk.x * CH + c);
        a0 = fmaf(bf_lo(g), w, a0);
        a1 = fmaf(bf_hi(g), w, a1);
    }
    uint o = (uint)f2bf(a0) | ((uint)f2bf(a1) << 16);
    *(uint*)(out + (size_t)wid * CH + c) = o;
}

// ---------------- H = relu(Y*W + b): Y bf16 [n,128], W fp32, H bf16 ----------
__global__ __launch_bounds__(256) void k_gemm_relu(const ushort* __restrict__ Y,
                                                   const float* __restrict__ W,
                                                   const float* __restrict__ bias,
                                                   ushort* __restrict__ H, int n) {
    __shared__ __align__(16) float As[64][68];  // [k][row]
    __shared__ __align__(16) float Bs[64][68];  // [k][col]
    int tid = threadIdx.x;
    int tx = tid & 15, ty = tid >> 4;
    int r0 = blockIdx.y * 64, c0 = blockIdx.x * 64;
    float acc[4][4] = {};
    for (int kt = 0; kt < 2; ++kt) {
#pragma unroll
        for (int it = 0; it < 2; ++it) {
            int f = tid + it * 256;     // 0..511
            int row = f >> 3;           // 0..63
            int kk = (f & 7) * 8;       // 0..56
            int r = r0 + row;
            uint4 v = make_uint4(0u, 0u, 0u, 0u);
            if (r < n) v = *(const uint4*)(Y + (size_t)r * CH + kt * 64 + kk);
            As[kk + 0][row] = bf_lo(v.x);
            As[kk + 1][row] = bf_hi(v.x);
            As[kk + 2][row] = bf_lo(v.y);
            As[kk + 3][row] = bf_hi(v.y);
            As[kk + 4][row] = bf_lo(v.z);
            As[kk + 5][row] = bf_hi(v.z);
            As[kk + 6][row] = bf_lo(v.w);
            As[kk + 7][row] = bf_hi(v.w);
        }
#pragma unroll
        for (int i = 0; i < 4; i++) {
            int f = tid + i * 256;
            int kk = f >> 4;
            int c4 = (f & 15) * 4;
            float4 v = *(const float4*)(W + (size_t)(kt * 64 + kk) * CH + c0 + c4);
            *(float4*)&Bs[kk][c4] = v;
        }
        __syncthreads();
#pragma unroll 8
        for (int k = 0; k < 64; ++k) {
            float4 a = *(float4*)&As[k][ty * 4];
            float4 b = *(float4*)&Bs[k][tx * 4];
            acc[0][0] += a.x * b.x; acc[0][1] += a.x * b.y; acc[0][2] += a.x * b.z; acc[0][3] += a.x * b.w;
            acc[1][0] += a.y * b.x; acc[1][1] += a.y * b.y; acc[1][2] += a.y * b.z; acc[1][3] += a.y * b.w;
            acc[2][0] += a.z * b.x; acc[2][1] += a.z * b.y; acc[2][2] += a.z * b.z; acc[2][3] += a.z * b.w;
            acc[3][0] += a.w * b.x; acc[3][1] += a.w * b.y; acc[3][2] += a.w * b.z; acc[3][3] += a.w * b.w;
        }
        __syncthreads();
    }
    float4 bv = *(const float4*)(bias + c0 + tx * 4);
#pragma unroll
    for (int i = 0; i < 4; i++) {
        int r = r0 + ty * 4 + i;
        if (r >= n) continue;
        float o0 = fmaxf(acc[i][0] + bv.x, 0.f);
        float o1 = fmaxf(acc[i][1] + bv.y, 0.f);
        float o2 = fmaxf(acc[i][2] + bv.z, 0.f);
        float o3 = fmaxf(acc[i][3] + bv.w, 0.f);
        uint2 o;
        o.x = (uint)f2bf(o0) | ((uint)f2bf(o1) << 16);
        o.y = (uint)f2bf(o2) | ((uint)f2bf(o3) << 16);
        *(uint2*)(H + (size_t)r * CH + c0 + tx * 4) = o;
    }
}

// ---------------- mean pool over sorted batch ids (bf16 in, fp32 out) --------
__global__ __launch_bounds__(256) void k_pool(const ushort* __restrict__ Z,
                                              const int* __restrict__ batch,
                                              float* __restrict__ Q, int n) {
    int g = blockIdx.x;
    int lo = 0, hi = n;
    while (lo < hi) { int m = (lo + hi) >> 1; if (batch[m] < g) lo = m + 1; else hi = m; }
    int start = lo;
    lo = start; hi = n;
    while (lo < hi) { int m = (lo + hi) >> 1; if (batch[m] < g + 1) lo = m + 1; else hi = m; }
    int end = lo;
    int w = threadIdx.x >> 6, lane = threadIdx.x & 63;
    float a0 = 0.f, a1 = 0.f;
    for (int i = start + w; i < end; i += 4) {
        uint gv = *(const uint*)(Z + (size_t)i * CH + lane * 2);
        a0 += bf_lo(gv);
        a1 += bf_hi(gv);
    }
    __shared__ float red[4][128];
    red[w][lane * 2] = a0;
    red[w][lane * 2 + 1] = a1;
    __syncthreads();
    if (threadIdx.x < 128) {
        int t = threadIdx.x;
        float s = red[0][t] + red[1][t] + red[2][t] + red[3][t];
        float c = (float)(end - start);
        Q[g * CH + t] = s / fmaxf(c, 1.f);
    }
}

// ---------------- fold W2*Wfc, b2*Wfc+bfc ----------------
__global__ __launch_bounds__(256) void k_foldw(const float* __restrict__ W2,
                                               const float* __restrict__ b2,
                                               const float* __restrict__ Wfc,
                                               const float* __restrict__ bfc,
                                               float* __restrict__ Wc,
                                               float* __restrict__ bc) {
    int t = blockIdx.x * 256 + threadIdx.x;
    if (t < CH * OC) {
        int k = t >> 6, o = t & 63;
        float acc = 0.f;
        for (int j = 0; j < CH; j++) acc += W2[k * CH + j] * Wfc[j * OC + o];
        Wc[t] = acc;
    } else if (t < CH * OC + OC) {
        int o = t - CH * OC;
        float acc = bfc[o];
        for (int j = 0; j < CH; j++) acc += b2[j] * Wfc[j * OC + o];
        bc[o] = acc;
    }
}

// ---------------- out = Q*Wc + bc ----------------
__global__ __launch_bounds__(256) void k_out(const float* __restrict__ Q,
                                             const float* __restrict__ Wc,
                                             const float* __restrict__ bc,
                                             float* __restrict__ out) {
    int t = blockIdx.x * 256 + threadIdx.x;  // 512*64
    int g = t >> 6, o = t & 63;
    float acc = bc[o];
    for (int k = 0; k < CH; k++) acc += Q[g * CH + k] * Wc[k * OC + o];
    out[t] = acc;
}

extern "C" void kernel_launch(void* const* d_in, const int* in_sizes, int n_in,
                              void* d_out, int out_size, void* d_ws, size_t ws_size,
                              hipStream_t stream) {
    const float* x   = (const float*)d_in[0];
    const float* W1  = (const float*)d_in[1];
    const float* b1  = (const float*)d_in[2];
    const float* W2  = (const float*)d_in[3];
    const float* b2  = (const float*)d_in[4];
    const float* Wfc = (const float*)d_in[5];
    const float* bfc = (const float*)d_in[6];
    const int* edges = (const int*)d_in[7];
    const int* batch = (const int*)d_in[8];

    const int n = in_sizes[8];        // 100000
    const int E = in_sizes[7] / 2;    // 1600000
    const int* esrc = edges;
    const int* edst = edges + E;

    char* p = (char*)d_ws;
    auto carve = [&](size_t bytes) {
        void* r = (void*)p;
        p += (bytes + 255) & ~(size_t)255;
        return r;
    };
    int*    deg       = (int*)carve((size_t)n * 4);
    float*  dinv      = (float*)carve((size_t)n * 4);
    int*    excl      = (int*)carve((size_t)n * 4);
    int*    bsums     = (int*)carve(512);
    int*    row_start = (int*)carve((size_t)(n + 1) * 4);
    int*    cursor    = (int*)carve((size_t)n * 4);
    int2*   ew        = (int2*)carve((size_t)E * 8);
    ushort* xb        = (ushort*)carve((size_t)n * CH * 2);  // also h1 later
    ushort* yb        = (ushort*)carve((size_t)n * CH * 2);  // also z later
    float*  q         = (float*)carve((size_t)NG * CH * 4);
    float*  Wc        = (float*)carve((size_t)CH * OC * 4);
    float*  bc        = (float*)carve((size_t)OC * 4);

    hipMemsetAsync(deg, 0, (size_t)n * 4, stream);

    int gE = (E + 255) / 256;
    int gN = (n + 255) / 256;
    int nScanBlocks = (n + 1023) / 1024;

    k_cvt<<<(n * CH / 4 + 255) / 256, 256, 0, stream>>>(x, xb, n * CH);
    k_deg<<<gE, 256, 0, stream>>>(edst, deg, E);
    k_scan1<<<nScanBlocks, 256, 0, stream>>>(deg, excl, bsums, dinv, n);
    k_scan2<<<1, 128, 0, stream>>>(bsums, nScanBlocks);
    k_scan3<<<gN, 256, 0, stream>>>(excl, bsums, row_start, cursor, n, E);
    k_scatter<<<gE, 256, 0, stream>>>(esrc, edst, dinv, cursor, ew, E);

    // y = A_hat * x   (xb -> yb)
    k_agg<<<(n + 3) / 4, 256, 0, stream>>>(xb, row_start, ew, dinv, yb, n);
    // h1 = relu(y*W1 + b1)   (yb -> xb)
    dim3 gg(CH / 64, (n + 63) / 64);
    k_gemm_relu<<<gg, 256, 0, stream>>>(yb, W1, b1, xb, n);
    // z = A_hat * h1   (xb -> yb)
    k_agg<<<(n + 3) / 4, 256, 0, stream>>>(xb, row_start, ew, dinv, yb, n);
    // q = pool(z)
    k_pool<<<NG, 256, 0, stream>>>(yb, batch, q, n);
    // folded tail
    k_foldw<<<(CH * OC + OC + 255) / 256, 256, 0, stream>>>(W2, b2, Wfc, bfc, Wc, bc);
    k_out<<<(NG * OC + 255) / 256, 256, 0, stream>>>(q, Wc, bc, (float*)d_out);
}

// Round 3
// 514.189 us; speedup vs baseline: 1.3088x; 1.2544x over previous
//
#include <hip/hip_runtime.h>
#include <stdint.h>

#define NN 100000
#define NE 1600000
#define CH 128
#define OC 64
#define NG 512

typedef unsigned int uint;
typedef unsigned short ushort;

__device__ __forceinline__ ushort f2bf(float f) {
    uint u = __float_as_uint(f);
    uint r = u + 0x7fffu + ((u >> 16) & 1u);  // round-to-nearest-even
    return (ushort)(r >> 16);
}
__device__ __forceinline__ float bf_lo(uint g) { return __uint_as_float(g << 16); }
__device__ __forceinline__ float bf_hi(uint g) { return __uint_as_float(g & 0xffff0000u); }

// ---------------- fp32 -> bf16 convert with dinv pre-scale ----------------
__global__ __launch_bounds__(256) void k_cvt(const float* __restrict__ x,
                                             const float* __restrict__ dinv,
                                             ushort* __restrict__ xb, int total) {
    int i = (blockIdx.x * 256 + threadIdx.x) * 4;
    if (i >= total) return;
    float d = dinv[i >> 7];           // 4 consecutive elems share the row (CH=128)
    float4 v = *(const float4*)(x + i);
    uint2 o;
    o.x = (uint)f2bf(v.x * d) | ((uint)f2bf(v.y * d) << 16);
    o.y = (uint)f2bf(v.z * d) | ((uint)f2bf(v.w * d) << 16);
    *(uint2*)(xb + i) = o;
}

// ---------------- degree ----------------
__global__ __launch_bounds__(256) void k_deg(const int* __restrict__ dst,
                                             int* __restrict__ deg, int E) {
    int i = blockIdx.x * 256 + threadIdx.x;
    if (i < E) atomicAdd(&deg[dst[i]], 1);
}

// ---------------- prefix scan (3-phase, 1024 elems/block) + dinv ----------------
__global__ __launch_bounds__(256) void k_scan1(const int* __restrict__ deg,
                                               int* __restrict__ excl,
                                               int* __restrict__ bsums,
                                               float* __restrict__ dinv, int n) {
    __shared__ int sd[256];
    int tid = threadIdx.x;
    int base = blockIdx.x * 1024 + tid * 4;
    int v[4];
#pragma unroll
    for (int i = 0; i < 4; i++) v[i] = (base + i < n) ? deg[base + i] : 0;
#pragma unroll
    for (int i = 0; i < 4; i++)
        if (base + i < n) dinv[base + i] = rsqrtf((float)v[i] + 1.0f);
    int tsum = v[0] + v[1] + v[2] + v[3];
    int val = tsum;
    sd[tid] = val; __syncthreads();
    for (int off = 1; off < 256; off <<= 1) {
        int t = (tid >= off) ? sd[tid - off] : 0;
        __syncthreads();
        val += t; sd[tid] = val;
        __syncthreads();
    }
    int run = val - tsum;
#pragma unroll
    for (int i = 0; i < 4; i++) {
        if (base + i < n) excl[base + i] = run;
        run += v[i];
    }
    if (tid == 255) bsums[blockIdx.x] = val;
}

__global__ __launch_bounds__(128) void k_scan2(int* __restrict__ bs, int nb) {
    __shared__ int sd[128];
    int tid = threadIdx.x;
    int v = (tid < nb) ? bs[tid] : 0;
    int val = v;
    sd[tid] = val; __syncthreads();
    for (int off = 1; off < 128; off <<= 1) {
        int t = (tid >= off) ? sd[tid - off] : 0;
        __syncthreads();
        val += t; sd[tid] = val;
        __syncthreads();
    }
    if (tid < nb) bs[tid] = val - v;
}

__global__ __launch_bounds__(256) void k_scan3(const int* __restrict__ excl,
                                               const int* __restrict__ boff,
                                               int* __restrict__ row_start,
                                               int* __restrict__ cursor,
                                               int n, int E) {
    int i = blockIdx.x * 256 + threadIdx.x;
    if (i < n) {
        int rs = excl[i] + boff[i >> 10];
        row_start[i] = rs;
        cursor[i] = rs;
    }
    if (i == 0) row_start[n] = E;
}

// ---------------- bucket edges by dst: src only (4B store) ----------------
__global__ __launch_bounds__(256) void k_scatter(const int* __restrict__ src,
                                                 const int* __restrict__ dst,
                                                 int* __restrict__ cursor,
                                                 int* __restrict__ ssrc, int E) {
    int i = blockIdx.x * 256 + threadIdx.x;
    if (i >= E) return;
    int s = src[i], d = dst[i];
    int pos = atomicAdd(&cursor[d], 1);
    ssrc[pos] = s;
}

// ------- aggregation: out = dinv_dst * (sum_e Hs[src_e] + Hs[dst]) -------
// Hs is pre-scaled by dinv. 8-way unrolled gather loop for MLP.
__global__ __launch_bounds__(256) void k_agg(const ushort* __restrict__ Hs,
                                             const int* __restrict__ rs,
                                             const int* __restrict__ ssrc,
                                             const float* __restrict__ dinv,
                                             ushort* __restrict__ out, int n) {
    int wid = (blockIdx.x << 2) | (threadIdx.x >> 6);
    int lane = threadIdx.x & 63;
    if (wid >= n) return;
    int uw = __builtin_amdgcn_readfirstlane(wid);
    int c = lane * 2;
    uint selfv = *(const uint*)(Hs + (size_t)uw * CH + c);
    float a0 = bf_lo(selfv);
    float a1 = bf_hi(selfv);
    float b0 = 0.f, b1 = 0.f;
    int e0 = rs[uw], e1 = rs[uw + 1];
    int e = e0;
    int m8 = e0 + ((e1 - e0) & ~7);
    for (; e < m8; e += 8) {
        int s0 = ssrc[e + 0], s1 = ssrc[e + 1], s2 = ssrc[e + 2], s3 = ssrc[e + 3];
        int s4 = ssrc[e + 4], s5 = ssrc[e + 5], s6 = ssrc[e + 6], s7 = ssrc[e + 7];
        uint g0 = *(const uint*)(Hs + ((s0 << 7) + c));
        uint g1 = *(const uint*)(Hs + ((s1 << 7) + c));
        uint g2 = *(const uint*)(Hs + ((s2 << 7) + c));
        uint g3 = *(const uint*)(Hs + ((s3 << 7) + c));
        uint g4 = *(const uint*)(Hs + ((s4 << 7) + c));
        uint g5 = *(const uint*)(Hs + ((s5 << 7) + c));
        uint g6 = *(const uint*)(Hs + ((s6 << 7) + c));
        uint g7 = *(const uint*)(Hs + ((s7 << 7) + c));
        a0 += bf_lo(g0) + bf_lo(g1); a1 += bf_hi(g0) + bf_hi(g1);
        b0 += bf_lo(g2) + bf_lo(g3); b1 += bf_hi(g2) + bf_hi(g3);
        a0 += bf_lo(g4) + bf_lo(g5); a1 += bf_hi(g4) + bf_hi(g5);
        b0 += bf_lo(g6) + bf_lo(g7); b1 += bf_hi(g6) + bf_hi(g7);
    }
    for (; e < e1; ++e) {
        int s = ssrc[e];
        uint g = *(const uint*)(Hs + ((s << 7) + c));
        a0 += bf_lo(g); a1 += bf_hi(g);
    }
    float d = dinv[uw];
    float o0 = d * (a0 + b0);
    float o1 = d * (a1 + b1);
    uint o = (uint)f2bf(o0) | ((uint)f2bf(o1) << 16);
    *(uint*)(out + (size_t)uw * CH + c) = o;
}

// --------- H = dinv_row * relu(Y*W + b): Y bf16 [n,128], out pre-scaled ------
__global__ __launch_bounds__(256) void k_gemm_relu(const ushort* __restrict__ Y,
                                                   const float* __restrict__ W,
                                                   const float* __restrict__ bias,
                                                   const float* __restrict__ dinv,
                                                   ushort* __restrict__ H, int n) {
    __shared__ __align__(16) float As[64][68];  // [k][row]
    __shared__ __align__(16) float Bs[64][68];  // [k][col]
    int tid = threadIdx.x;
    int tx = tid & 15, ty = tid >> 4;
    int r0 = blockIdx.y * 64, c0 = blockIdx.x * 64;
    float acc[4][4] = {};
    for (int kt = 0; kt < 2; ++kt) {
#pragma unroll
        for (int it = 0; it < 2; ++it) {
            int f = tid + it * 256;     // 0..511
            int row = f >> 3;           // 0..63
            int kk = (f & 7) * 8;       // 0..56
            int r = r0 + row;
            uint4 v = make_uint4(0u, 0u, 0u, 0u);
            if (r < n) v = *(const uint4*)(Y + (size_t)r * CH + kt * 64 + kk);
            As[kk + 0][row] = bf_lo(v.x);
            As[kk + 1][row] = bf_hi(v.x);
            As[kk + 2][row] = bf_lo(v.y);
            As[kk + 3][row] = bf_hi(v.y);
            As[kk + 4][row] = bf_lo(v.z);
            As[kk + 5][row] = bf_hi(v.z);
            As[kk + 6][row] = bf_lo(v.w);
            As[kk + 7][row] = bf_hi(v.w);
        }
#pragma unroll
        for (int i = 0; i < 4; i++) {
            int f = tid + i * 256;
            int kk = f >> 4;
            int c4 = (f & 15) * 4;
            float4 v = *(const float4*)(W + (size_t)(kt * 64 + kk) * CH + c0 + c4);
            *(float4*)&Bs[kk][c4] = v;
        }
        __syncthreads();
#pragma unroll 8
        for (int k = 0; k < 64; ++k) {
            float4 a = *(float4*)&As[k][ty * 4];
            float4 b = *(float4*)&Bs[k][tx * 4];
            acc[0][0] += a.x * b.x; acc[0][1] += a.x * b.y; acc[0][2] += a.x * b.z; acc[0][3] += a.x * b.w;
            acc[1][0] += a.y * b.x; acc[1][1] += a.y * b.y; acc[1][2] += a.y * b.z; acc[1][3] += a.y * b.w;
            acc[2][0] += a.z * b.x; acc[2][1] += a.z * b.y; acc[2][2] += a.z * b.z; acc[2][3] += a.z * b.w;
            acc[3][0] += a.w * b.x; acc[3][1] += a.w * b.y; acc[3][2] += a.w * b.z; acc[3][3] += a.w * b.w;
        }
        __syncthreads();
    }
    float4 bv = *(const float4*)(bias + c0 + tx * 4);
#pragma unroll
    for (int i = 0; i < 4; i++) {
        int r = r0 + ty * 4 + i;
        if (r >= n) continue;
        float d = dinv[r];
        float o0 = d * fmaxf(acc[i][0] + bv.x, 0.f);
        float o1 = d * fmaxf(acc[i][1] + bv.y, 0.f);
        float o2 = d * fmaxf(acc[i][2] + bv.z, 0.f);
        float o3 = d * fmaxf(acc[i][3] + bv.w, 0.f);
        uint2 o;
        o.x = (uint)f2bf(o0) | ((uint)f2bf(o1) << 16);
        o.y = (uint)f2bf(o2) | ((uint)f2bf(o3) << 16);
        *(uint2*)(H + (size_t)r * CH + c0 + tx * 4) = o;
    }
}

// ---------------- mean pool over sorted batch ids (bf16 in, fp32 out) --------
__global__ __launch_bounds__(256) void k_pool(const ushort* __restrict__ Z,
                                              const int* __restrict__ batch,
                                              float* __restrict__ Q, int n) {
    int g = blockIdx.x;
    int lo = 0, hi = n;
    while (lo < hi) { int m = (lo + hi) >> 1; if (batch[m] < g) lo = m + 1; else hi = m; }
    int start = lo;
    lo = start; hi = n;
    while (lo < hi) { int m = (lo + hi) >> 1; if (batch[m] < g + 1) lo = m + 1; else hi = m; }
    int end = lo;
    int w = threadIdx.x >> 6, lane = threadIdx.x & 63;
    float a0 = 0.f, a1 = 0.f;
    for (int i = start + w; i < end; i += 4) {
        uint gv = *(const uint*)(Z + (size_t)i * CH + lane * 2);
        a0 += bf_lo(gv);
        a1 += bf_hi(gv);
    }
    __shared__ float red[4][128];
    red[w][lane * 2] = a0;
    red[w][lane * 2 + 1] = a1;
    __syncthreads();
    if (threadIdx.x < 128) {
        int t = threadIdx.x;
        float s = red[0][t] + red[1][t] + red[2][t] + red[3][t];
        float c = (float)(end - start);
        Q[g * CH + t] = s / fmaxf(c, 1.f);
    }
}

// ---------------- fold W2*Wfc, b2*Wfc+bfc ----------------
__global__ __launch_bounds__(256) void k_foldw(const float* __restrict__ W2,
                                               const float* __restrict__ b2,
                                               const float* __restrict__ Wfc,
                                               const float* __restrict__ bfc,
                                               float* __restrict__ Wc,
                                               float* __restrict__ bc) {
    int t = blockIdx.x * 256 + threadIdx.x;
    if (t < CH * OC) {
        int k = t >> 6, o = t & 63;
        float acc = 0.f;
        for (int j = 0; j < CH; j++) acc += W2[k * CH + j] * Wfc[j * OC + o];
        Wc[t] = acc;
    } else if (t < CH * OC + OC) {
        int o = t - CH * OC;
        float acc = bfc[o];
        for (int j = 0; j < CH; j++) acc += b2[j] * Wfc[j * OC + o];
        bc[o] = acc;
    }
}

// ---------------- out = Q*Wc + bc ----------------
__global__ __launch_bounds__(256) void k_out(const float* __restrict__ Q,
                                             const float* __restrict__ Wc,
                                             const float* __restrict__ bc,
                                             float* __restrict__ out) {
    int t = blockIdx.x * 256 + threadIdx.x;  // 512*64
    int g = t >> 6, o = t & 63;
    float acc = bc[o];
    for (int k = 0; k < CH; k++) acc += Q[g * CH + k] * Wc[k * OC + o];
    out[t] = acc;
}

extern "C" void kernel_launch(void* const* d_in, const int* in_sizes, int n_in,
                              void* d_out, int out_size, void* d_ws, size_t ws_size,
                              hipStream_t stream) {
    const float* x   = (const float*)d_in[0];
    const float* W1  = (const float*)d_in[1];
    const float* b1  = (const float*)d_in[2];
    const float* W2  = (const float*)d_in[3];
    const float* b2  = (const float*)d_in[4];
    const float* Wfc = (const float*)d_in[5];
    const float* bfc = (const float*)d_in[6];
    const int* edges = (const int*)d_in[7];
    const int* batch = (const int*)d_in[8];

    const int n = in_sizes[8];        // 100000
    const int E = in_sizes[7] / 2;    // 1600000
    const int* esrc = edges;
    const int* edst = edges + E;

    char* p = (char*)d_ws;
    auto carve = [&](size_t bytes) {
        void* r = (void*)p;
        p += (bytes + 255) & ~(size_t)255;
        return r;
    };
    int*    deg       = (int*)carve((size_t)n * 4);
    float*  dinv      = (float*)carve((size_t)n * 4);
    int*    excl      = (int*)carve((size_t)n * 4);
    int*    bsums     = (int*)carve(512);
    int*    row_start = (int*)carve((size_t)(n + 1) * 4);
    int*    cursor    = (int*)carve((size_t)n * 4);
    int*    ssrc      = (int*)carve((size_t)E * 4);
    ushort* xb        = (ushort*)carve((size_t)n * CH * 2);  // also h1 later
    ushort* yb        = (ushort*)carve((size_t)n * CH * 2);  // also z later
    float*  q         = (float*)carve((size_t)NG * CH * 4);
    float*  Wc        = (float*)carve((size_t)CH * OC * 4);
    float*  bc        = (float*)carve((size_t)OC * 4);

    hipMemsetAsync(deg, 0, (size_t)n * 4, stream);

    int gE = (E + 255) / 256;
    int gN = (n + 255) / 256;
    int nScanBlocks = (n + 1023) / 1024;

    k_deg<<<gE, 256, 0, stream>>>(edst, deg, E);
    k_scan1<<<nScanBlocks, 256, 0, stream>>>(deg, excl, bsums, dinv, n);
    k_scan2<<<1, 128, 0, stream>>>(bsums, nScanBlocks);
    k_scan3<<<gN, 256, 0, stream>>>(excl, bsums, row_start, cursor, n, E);
    k_cvt<<<(n * CH / 4 + 255) / 256, 256, 0, stream>>>(x, dinv, xb, n * CH);
    k_scatter<<<gE, 256, 0, stream>>>(esrc, edst, cursor, ssrc, E);

    // y = dinv*(sum Xs + self)   (xb -> yb), plain bf16 y
    k_agg<<<(n + 3) / 4, 256, 0, stream>>>(xb, row_start, ssrc, dinv, yb, n);
    // h1s = dinv*relu(y*W1 + b1)   (yb -> xb), pre-scaled
    dim3 gg(CH / 64, (n + 63) / 64);
    k_gemm_relu<<<gg, 256, 0, stream>>>(yb, W1, b1, dinv, xb, n);
    // z = dinv*(sum H1s + self)   (xb -> yb), plain
    k_agg<<<(n + 3) / 4, 256, 0, stream>>>(xb, row_start, ssrc, dinv, yb, n);
    // q = pool(z)
    k_pool<<<NG, 256, 0, stream>>>(yb, batch, q, n);
    // folded tail
    k_foldw<<<(CH * OC + OC + 255) / 256, 256, 0, stream>>>(W2, b2, Wfc, bfc, Wc, bc);
    k_out<<<(NG * OC + 255) / 256, 256, 0, stream>>>(q, Wc, bc, (float*)d_out);
}

// Round 4
// 362.392 us; speedup vs baseline: 1.8571x; 1.4189x over previous
//
#include <hip/hip_runtime.h>
#include <stdint.h>

#define NN 100000
#define NE 1600000
#define CH 128
#define OC 64
#define NG 512
#define NBLK 256      // partition blocks
#define NBMAX 4096    // max coarse buckets (nodes/256)

typedef unsigned int uint;
typedef unsigned short ushort;

__device__ __forceinline__ ushort f2bf(float f) {
    uint u = __float_as_uint(f);
    uint r = u + 0x7fffu + ((u >> 16) & 1u);  // round-to-nearest-even
    return (ushort)(r >> 16);
}
__device__ __forceinline__ float bf_lo(uint g) { return __uint_as_float(g << 16); }
__device__ __forceinline__ float bf_hi(uint g) { return __uint_as_float(g & 0xffff0000u); }

// ---------------- bucket histogram: bh[blk*NB + b] ----------------
__global__ __launch_bounds__(256) void k_hist(const int* __restrict__ dst,
                                              int* __restrict__ bh,
                                              int E, int NB, int chunk) {
    __shared__ int h[NBMAX];
    int blk = blockIdx.x, tid = threadIdx.x;
    for (int j = tid; j < NB; j += 256) h[j] = 0;
    __syncthreads();
    int lo = blk * chunk, hi = min(E, lo + chunk);
    for (int i = lo + tid; i < hi; i += 256) atomicAdd(&h[dst[i] >> 8], 1);
    __syncthreads();
    for (int j = tid; j < NB; j += 256) bh[blk * NB + j] = h[j];
}

// ---------------- transpose [R][C] -> [C][R] ----------------
__global__ __launch_bounds__(256) void k_transpose(const int* __restrict__ in,
                                                   int* __restrict__ out,
                                                   int R, int C) {
    __shared__ int t[32][33];
    int c0 = blockIdx.x * 32, r0 = blockIdx.y * 32;
    int lx = threadIdx.x & 31, ly = threadIdx.x >> 5;  // 8 rows per pass
#pragma unroll
    for (int i = 0; i < 32; i += 8) {
        int r = r0 + ly + i, c = c0 + lx;
        t[ly + i][lx] = (r < R && c < C) ? in[r * C + c] : 0;
    }
    __syncthreads();
#pragma unroll
    for (int i = 0; i < 32; i += 8) {
        int c = c0 + ly + i, r = r0 + lx;
        if (c < C && r < R) out[c * R + r] = t[lx][ly + i];
    }
}

// ---------------- prefix scan (3-phase, 1024 elems/block) ----------------
__global__ __launch_bounds__(256) void k_scan1(const int* __restrict__ in,
                                               int* __restrict__ excl,
                                               int* __restrict__ bsums, int T) {
    __shared__ int sd[256];
    int tid = threadIdx.x;
    int base = blockIdx.x * 1024 + tid * 4;
    int v[4];
#pragma unroll
    for (int i = 0; i < 4; i++) v[i] = (base + i < T) ? in[base + i] : 0;
    int tsum = v[0] + v[1] + v[2] + v[3];
    int val = tsum;
    sd[tid] = val; __syncthreads();
    for (int off = 1; off < 256; off <<= 1) {
        int t = (tid >= off) ? sd[tid - off] : 0;
        __syncthreads();
        val += t; sd[tid] = val;
        __syncthreads();
    }
    int run = val - tsum;
#pragma unroll
    for (int i = 0; i < 4; i++) {
        if (base + i < T) excl[base + i] = run;
        run += v[i];
    }
    if (tid == 255) bsums[blockIdx.x] = val;
}

__global__ __launch_bounds__(128) void k_scan2(int* __restrict__ bs, int nb) {
    __shared__ int sd[128];
    int tid = threadIdx.x;
    int v = (tid < nb) ? bs[tid] : 0;
    int val = v;
    sd[tid] = val; __syncthreads();
    for (int off = 1; off < 128; off <<= 1) {
        int t = (tid >= off) ? sd[tid - off] : 0;
        __syncthreads();
        val += t; sd[tid] = val;
        __syncthreads();
    }
    if (tid < nb) bs[tid] = val - v;
}

__global__ __launch_bounds__(256) void k_scan3(int* __restrict__ excl,
                                               const int* __restrict__ boff, int T) {
    int i = blockIdx.x * 256 + threadIdx.x;
    if (i < T) excl[i] += boff[i >> 10];
}

// ------- partition: write (src,dst) into per-(bucket,block) segments -------
__global__ __launch_bounds__(256) void k_part(const int* __restrict__ src,
                                              const int* __restrict__ dst,
                                              const int* __restrict__ off,
                                              int2* __restrict__ ebuf,
                                              int E, int NB, int chunk) {
    __shared__ int cur[NBMAX];
    int blk = blockIdx.x, tid = threadIdx.x;
    for (int j = tid; j < NB; j += 256) cur[j] = off[j * NBLK + blk];
    __syncthreads();
    int lo = blk * chunk, hi = min(E, lo + chunk);
    for (int i = lo + tid; i < hi; i += 256) {
        int s = src[i], d = dst[i];
        int pos = atomicAdd(&cur[d >> 8], 1);
        int2 pk; pk.x = s; pk.y = d;
        ebuf[pos] = pk;
    }
}

// ------- CSR finalize per bucket: deg, dinv, row_start, local scatter -------
__global__ __launch_bounds__(256) void k_csr(const int2* __restrict__ ebuf,
                                             const int* __restrict__ off,
                                             int* __restrict__ row_start,
                                             float* __restrict__ dinv,
                                             int* __restrict__ ssrc,
                                             int n, int NB, int E) {
    __shared__ int cnt[256], sc[256], cur[256];
    int b = blockIdx.x, tid = threadIdx.x;
    int node0 = b << 8;
    int bstart = off[b * NBLK];
    int bend = (b + 1 < NB) ? off[(b + 1) * NBLK] : E;
    cnt[tid] = 0;
    __syncthreads();
    for (int i = bstart + tid; i < bend; i += 256)
        atomicAdd(&cnt[ebuf[i].y - node0], 1);
    __syncthreads();
    int v = cnt[tid];
    int val = v;
    sc[tid] = val; __syncthreads();
    for (int o = 1; o < 256; o <<= 1) {
        int t = (tid >= o) ? sc[tid - o] : 0;
        __syncthreads();
        val += t; sc[tid] = val;
        __syncthreads();
    }
    int excl = val - v;
    int node = node0 + tid;
    if (node < n) {
        row_start[node] = bstart + excl;
        dinv[node] = rsqrtf((float)v + 1.0f);
    }
    cur[tid] = bstart + excl;
    if (b == NB - 1 && tid == 0) row_start[n] = E;
    __syncthreads();
    for (int i = bstart + tid; i < bend; i += 256) {
        int2 e = ebuf[i];
        int pos = atomicAdd(&cur[e.y - node0], 1);
        ssrc[pos] = e.x;
    }
}

// ---------------- fp32 -> bf16 convert with dinv pre-scale ----------------
__global__ __launch_bounds__(256) void k_cvt(const float* __restrict__ x,
                                             const float* __restrict__ dinv,
                                             ushort* __restrict__ xb, int total) {
    int i = (blockIdx.x * 256 + threadIdx.x) * 4;
    if (i >= total) return;
    float d = dinv[i >> 7];
    float4 v = *(const float4*)(x + i);
    uint2 o;
    o.x = (uint)f2bf(v.x * d) | ((uint)f2bf(v.y * d) << 16);
    o.y = (uint)f2bf(v.z * d) | ((uint)f2bf(v.w * d) << 16);
    *(uint2*)(xb + i) = o;
}

// ------- aggregation: out = dinv_dst * (sum_e Hs[src_e] + Hs[dst]) -------
__global__ __launch_bounds__(256) void k_agg(const ushort* __restrict__ Hs,
                                             const int* __restrict__ rs,
                                             const int* __restrict__ ssrc,
                                             const float* __restrict__ dinv,
                                             ushort* __restrict__ out, int n) {
    int wid = (blockIdx.x << 2) | (threadIdx.x >> 6);
    int lane = threadIdx.x & 63;
    if (wid >= n) return;
    int uw = __builtin_amdgcn_readfirstlane(wid);
    int c = lane * 2;
    uint selfv = *(const uint*)(Hs + (size_t)uw * CH + c);
    float a0 = bf_lo(selfv);
    float a1 = bf_hi(selfv);
    float b0 = 0.f, b1 = 0.f;
    int e0 = rs[uw], e1 = rs[uw + 1];
    int e = e0;
    int m8 = e0 + ((e1 - e0) & ~7);
    for (; e < m8; e += 8) {
        int s0 = ssrc[e + 0], s1 = ssrc[e + 1], s2 = ssrc[e + 2], s3 = ssrc[e + 3];
        int s4 = ssrc[e + 4], s5 = ssrc[e + 5], s6 = ssrc[e + 6], s7 = ssrc[e + 7];
        uint g0 = *(const uint*)(Hs + ((s0 << 7) + c));
        uint g1 = *(const uint*)(Hs + ((s1 << 7) + c));
        uint g2 = *(const uint*)(Hs + ((s2 << 7) + c));
        uint g3 = *(const uint*)(Hs + ((s3 << 7) + c));
        uint g4 = *(const uint*)(Hs + ((s4 << 7) + c));
        uint g5 = *(const uint*)(Hs + ((s5 << 7) + c));
        uint g6 = *(const uint*)(Hs + ((s6 << 7) + c));
        uint g7 = *(const uint*)(Hs + ((s7 << 7) + c));
        a0 += bf_lo(g0) + bf_lo(g1); a1 += bf_hi(g0) + bf_hi(g1);
        b0 += bf_lo(g2) + bf_lo(g3); b1 += bf_hi(g2) + bf_hi(g3);
        a0 += bf_lo(g4) + bf_lo(g5); a1 += bf_hi(g4) + bf_hi(g5);
        b0 += bf_lo(g6) + bf_lo(g7); b1 += bf_hi(g6) + bf_hi(g7);
    }
    for (; e < e1; ++e) {
        int s = ssrc[e];
        uint g = *(const uint*)(Hs + ((s << 7) + c));
        a0 += bf_lo(g); a1 += bf_hi(g);
    }
    float d = dinv[uw];
    float o0 = d * (a0 + b0);
    float o1 = d * (a1 + b1);
    uint o = (uint)f2bf(o0) | ((uint)f2bf(o1) << 16);
    *(uint*)(out + (size_t)uw * CH + c) = o;
}

// --------- H = dinv_row * relu(Y*W + b): Y bf16 [n,128], out pre-scaled ------
__global__ __launch_bounds__(256) void k_gemm_relu(const ushort* __restrict__ Y,
                                                   const float* __restrict__ W,
                                                   const float* __restrict__ bias,
                                                   const float* __restrict__ dinv,
                                                   ushort* __restrict__ H, int n) {
    __shared__ __align__(16) float As[64][68];  // [k][row]
    __shared__ __align__(16) float Bs[64][68];  // [k][col]
    int tid = threadIdx.x;
    int tx = tid & 15, ty = tid >> 4;
    int r0 = blockIdx.y * 64, c0 = blockIdx.x * 64;
    float acc[4][4] = {};
    for (int kt = 0; kt < 2; ++kt) {
#pragma unroll
        for (int it = 0; it < 2; ++it) {
            int f = tid + it * 256;
            int row = f >> 3;
            int kk = (f & 7) * 8;
            int r = r0 + row;
            uint4 v = make_uint4(0u, 0u, 0u, 0u);
            if (r < n) v = *(const uint4*)(Y + (size_t)r * CH + kt * 64 + kk);
            As[kk + 0][row] = bf_lo(v.x);
            As[kk + 1][row] = bf_hi(v.x);
            As[kk + 2][row] = bf_lo(v.y);
            As[kk + 3][row] = bf_hi(v.y);
            As[kk + 4][row] = bf_lo(v.z);
            As[kk + 5][row] = bf_hi(v.z);
            As[kk + 6][row] = bf_lo(v.w);
            As[kk + 7][row] = bf_hi(v.w);
        }
#pragma unroll
        for (int i = 0; i < 4; i++) {
            int f = tid + i * 256;
            int kk = f >> 4;
            int c4 = (f & 15) * 4;
            float4 v = *(const float4*)(W + (size_t)(kt * 64 + kk) * CH + c0 + c4);
            *(float4*)&Bs[kk][c4] = v;
        }
        __syncthreads();
#pragma unroll 8
        for (int k = 0; k < 64; ++k) {
            float4 a = *(float4*)&As[k][ty * 4];
            float4 b = *(float4*)&Bs[k][tx * 4];
            acc[0][0] += a.x * b.x; acc[0][1] += a.x * b.y; acc[0][2] += a.x * b.z; acc[0][3] += a.x * b.w;
            acc[1][0] += a.y * b.x; acc[1][1] += a.y * b.y; acc[1][2] += a.y * b.z; acc[1][3] += a.y * b.w;
            acc[2][0] += a.z * b.x; acc[2][1] += a.z * b.y; acc[2][2] += a.z * b.z; acc[2][3] += a.z * b.w;
            acc[3][0] += a.w * b.x; acc[3][1] += a.w * b.y; acc[3][2] += a.w * b.z; acc[3][3] += a.w * b.w;
        }
        __syncthreads();
    }
    float4 bv = *(const float4*)(bias + c0 + tx * 4);
#pragma unroll
    for (int i = 0; i < 4; i++) {
        int r = r0 + ty * 4 + i;
        if (r >= n) continue;
        float d = dinv[r];
        float o0 = d * fmaxf(acc[i][0] + bv.x, 0.f);
        float o1 = d * fmaxf(acc[i][1] + bv.y, 0.f);
        float o2 = d * fmaxf(acc[i][2] + bv.z, 0.f);
        float o3 = d * fmaxf(acc[i][3] + bv.w, 0.f);
        uint2 o;
        o.x = (uint)f2bf(o0) | ((uint)f2bf(o1) << 16);
        o.y = (uint)f2bf(o2) | ((uint)f2bf(o3) << 16);
        *(uint2*)(H + (size_t)r * CH + c0 + tx * 4) = o;
    }
}

// ---------------- mean pool over sorted batch ids (bf16 in, fp32 out) --------
__global__ __launch_bounds__(256) void k_pool(const ushort* __restrict__ Z,
                                              const int* __restrict__ batch,
                                              float* __restrict__ Q, int n) {
    int g = blockIdx.x;
    int lo = 0, hi = n;
    while (lo < hi) { int m = (lo + hi) >> 1; if (batch[m] < g) lo = m + 1; else hi = m; }
    int start = lo;
    lo = start; hi = n;
    while (lo < hi) { int m = (lo + hi) >> 1; if (batch[m] < g + 1) lo = m + 1; else hi = m; }
    int end = lo;
    int w = threadIdx.x >> 6, lane = threadIdx.x & 63;
    float a0 = 0.f, a1 = 0.f;
    for (int i = start + w; i < end; i += 4) {
        uint gv = *(const uint*)(Z + (size_t)i * CH + lane * 2);
        a0 += bf_lo(gv);
        a1 += bf_hi(gv);
    }
    __shared__ float red[4][128];
    red[w][lane * 2] = a0;
    red[w][lane * 2 + 1] = a1;
    __syncthreads();
    if (threadIdx.x < 128) {
        int t = threadIdx.x;
        float s = red[0][t] + red[1][t] + red[2][t] + red[3][t];
        float c = (float)(end - start);
        Q[g * CH + t] = s / fmaxf(c, 1.f);
    }
}

// ---------------- fold W2*Wfc, b2*Wfc+bfc ----------------
__global__ __launch_bounds__(256) void k_foldw(const float* __restrict__ W2,
                                               const float* __restrict__ b2,
                                               const float* __restrict__ Wfc,
                                               const float* __restrict__ bfc,
                                               float* __restrict__ Wc,
                                               float* __restrict__ bc) {
    int t = blockIdx.x * 256 + threadIdx.x;
    if (t < CH * OC) {
        int k = t >> 6, o = t & 63;
        float acc = 0.f;
        for (int j = 0; j < CH; j++) acc += W2[k * CH + j] * Wfc[j * OC + o];
        Wc[t] = acc;
    } else if (t < CH * OC + OC) {
        int o = t - CH * OC;
        float acc = bfc[o];
        for (int j = 0; j < CH; j++) acc += b2[j] * Wfc[j * OC + o];
        bc[o] = acc;
    }
}

// ---------------- out = Q*Wc + bc ----------------
__global__ __launch_bounds__(256) void k_out(const float* __restrict__ Q,
                                             const float* __restrict__ Wc,
                                             const float* __restrict__ bc,
                                             float* __restrict__ out) {
    int t = blockIdx.x * 256 + threadIdx.x;
    int g = t >> 6, o = t & 63;
    float acc = bc[o];
    for (int k = 0; k < CH; k++) acc += Q[g * CH + k] * Wc[k * OC + o];
    out[t] = acc;
}

extern "C" void kernel_launch(void* const* d_in, const int* in_sizes, int n_in,
                              void* d_out, int out_size, void* d_ws, size_t ws_size,
                              hipStream_t stream) {
    const float* x   = (const float*)d_in[0];
    const float* W1  = (const float*)d_in[1];
    const float* b1  = (const float*)d_in[2];
    const float* W2  = (const float*)d_in[3];
    const float* b2  = (const float*)d_in[4];
    const float* Wfc = (const float*)d_in[5];
    const float* bfc = (const float*)d_in[6];
    const int* edges = (const int*)d_in[7];
    const int* batch = (const int*)d_in[8];

    const int n = in_sizes[8];        // 100000
    const int E = in_sizes[7] / 2;    // 1600000
    const int* esrc = edges;
    const int* edst = edges + E;

    const int NB = (n + 255) >> 8;            // 391 coarse buckets
    const int T = NB * NBLK;                  // blockhist entries
    const int chunk = (E + NBLK - 1) / NBLK;  // edges per partition block

    char* p = (char*)d_ws;
    auto carve = [&](size_t bytes) {
        void* r = (void*)p;
        p += (bytes + 255) & ~(size_t)255;
        return r;
    };
    int*    bh        = (int*)carve((size_t)T * 4);
    int*    bhT       = (int*)carve((size_t)T * 4);
    int*    off       = (int*)carve((size_t)T * 4);   // scanned offsets
    int*    bsums     = (int*)carve(512);
    int2*   ebuf      = (int2*)carve((size_t)E * 8);
    int*    row_start = (int*)carve((size_t)(n + 1) * 4);
    float*  dinv      = (float*)carve((size_t)n * 4);
    int*    ssrc      = (int*)carve((size_t)E * 4);
    ushort* xb        = (ushort*)carve((size_t)n * CH * 2);
    ushort* yb        = (ushort*)carve((size_t)n * CH * 2);
    float*  q         = (float*)carve((size_t)NG * CH * 4);
    float*  Wc        = (float*)carve((size_t)CH * OC * 4);
    float*  bc        = (float*)carve((size_t)OC * 4);

    int nScanBlocks = (T + 1023) / 1024;      // 98

    // CSR build (atomic-free global ordering)
    k_hist<<<NBLK, 256, 0, stream>>>(edst, bh, E, NB, chunk);
    dim3 gt((NB + 31) / 32, (NBLK + 31) / 32);
    k_transpose<<<gt, 256, 0, stream>>>(bh, bhT, NBLK, NB);
    k_scan1<<<nScanBlocks, 256, 0, stream>>>(bhT, off, bsums, T);
    k_scan2<<<1, 128, 0, stream>>>(bsums, nScanBlocks);
    k_scan3<<<(T + 255) / 256, 256, 0, stream>>>(off, bsums, T);
    k_part<<<NBLK, 256, 0, stream>>>(esrc, edst, off, ebuf, E, NB, chunk);
    k_csr<<<NB, 256, 0, stream>>>(ebuf, off, row_start, dinv, ssrc, n, NB, E);

    // features
    k_cvt<<<(n * CH / 4 + 255) / 256, 256, 0, stream>>>(x, dinv, xb, n * CH);
    // y = dinv*(sum Xs + self)   (xb -> yb)
    k_agg<<<(n + 3) / 4, 256, 0, stream>>>(xb, row_start, ssrc, dinv, yb, n);
    // h1s = dinv*relu(y*W1 + b1)   (yb -> xb)
    dim3 gg(CH / 64, (n + 63) / 64);
    k_gemm_relu<<<gg, 256, 0, stream>>>(yb, W1, b1, dinv, xb, n);
    // z = dinv*(sum H1s + self)   (xb -> yb)
    k_agg<<<(n + 3) / 4, 256, 0, stream>>>(xb, row_start, ssrc, dinv, yb, n);
    // q = pool(z)
    k_pool<<<NG, 256, 0, stream>>>(yb, batch, q, n);
    // folded tail
    k_foldw<<<(CH * OC + OC + 255) / 256, 256, 0, stream>>>(W2, b2, Wfc, bfc, Wc, bc);
    k_out<<<(NG * OC + 255) / 256, 256, 0, stream>>>(q, Wc, bc, (float*)d_out);
}